// Round 29
// baseline (151.945 us; speedup 1.0000x reference)
//
#include <hip/hip_runtime.h>
#include <hip/hip_bf16.h>

// ============================================================================
// R28: champion (143.7 = v21-k2 + k3v2) with the ledger hole filled:
// k2 = v22 (depth-2 T-prefetch + A-prefetch-1 + HW-cvt/trunc-lo) at rep=1
// - never measured single-shot (R25 ran x5 only, ~97/rep amplified).
// k1/k3v2/k4 unchanged from the 143.7 run.
// ============================================================================

// Problem constants
#define NB      32
#define INF     128
#define NPIX    64
#define TSP     16
#define OUTF    32
#define FF      16
#define D_IN    768
#define D_OUT   8192
#define NCOL    (D_OUT*FF)   // 131072
#define OUTCH   160
#define BSTRIDE 655360
#define NKS     24           // K-steps of 32 (768/32)
#define ALO     24576        // Af lo-part offset (ushorts)

typedef __attribute__((ext_vector_type(8))) short short8v;
typedef __attribute__((ext_vector_type(4))) float f32x4;

static __device__ __forceinline__ ushort f2bf(float f) {   // RNE (k1)
    union { float f; unsigned u; } v; v.f = f;
    return (ushort)((v.u + 0x7FFF + ((v.u >> 16) & 1)) >> 16);
}
static __device__ __forceinline__ float bf2f(ushort h) {
    union { unsigned u; float f; } v; v.u = ((unsigned)h) << 16; return v.f;
}
static __device__ __forceinline__ ushort f2bf_hw(float f) {
    __hip_bfloat16 b = __float2bfloat16(f);
    return *reinterpret_cast<ushort*>(&b);
}

// K1: fused strided conv + x->out copy; emits split-bf16 MFMA A-fragments.
__global__ __launch_bounds__(256) void k1_conv_copy(
    const float* __restrict__ x, const float* __restrict__ wc,
    float* __restrict__ out, ushort* __restrict__ Af)
{
    __shared__ float sW[3*128*16];
    __shared__ float sP[16][16][3];
    const int b   = blockIdx.x >> 4;
    const int oi  = blockIdx.x & 15;
    const int tid = threadIdx.x;
    for (int idx = tid; idx < 6144; idx += 256) sW[idx] = wc[idx];
    __syncthreads();
    const int icg = tid >> 4;
    const int j   = tid & 15;
    float a0 = 0.f, a1 = 0.f, a2 = 0.f;
    for (int ic8 = 0; ic8 < 8; ++ic8) {
        const int ic = icg*8 + ic8;
        #pragma unroll
        for (int ki = 0; ki < 4; ++ki) {
            const int row = 4*oi + ki;
            const float4 xv = *(const float4*)(x + ((size_t)(b*INF+ic)*NPIX + row)*NPIX + 4*j);
            *(float4*)(out + ((size_t)(b*OUTCH+ic)*NPIX + row)*NPIX + 4*j) = xv;
            const float* w0 = sW + ((0*INF+ic)*4 + ki)*4;
            const float* w1 = sW + ((1*INF+ic)*4 + ki)*4;
            const float* w2 = sW + ((2*INF+ic)*4 + ki)*4;
            a0 += xv.x*w0[0] + xv.y*w0[1] + xv.z*w0[2] + xv.w*w0[3];
            a1 += xv.x*w1[0] + xv.y*w1[1] + xv.z*w1[2] + xv.w*w1[3];
            a2 += xv.x*w2[0] + xv.y*w2[1] + xv.z*w2[2] + xv.w*w2[3];
        }
    }
    sP[icg][j][0] = a0; sP[icg][j][1] = a1; sP[icg][j][2] = a2;
    __syncthreads();
    if (tid < 48) {
        const int c3 = tid >> 4, jj = tid & 15;
        float s = 0.f;
        #pragma unroll
        for (int g = 0; g < 16; ++g) s += sP[g][jj][c3];
        const int k  = c3*256 + oi*16 + jj;
        const ushort hi = f2bf(s);
        const ushort lo = f2bf(s - bf2f(hi));
        const int fa = (k>>5)*1024 + (b>>4)*512 + ((((k>>3)&3)<<4) + (b&15))*8 + (k&7);
        Af[fa] = hi; Af[ALO + fa] = lo;
    }
}

// K2 v22 @ rep=1: split-bf16 MFMA + depth-2 T-prefetch + A-prefetch-1 +
// HW-cvt/trunc-lo. Correctness proven in R25 (x5, absmax 0.04211426).
__global__ __launch_bounds__(512, 4) void k2_gemm(
    const ushort* __restrict__ Af, const float* __restrict__ Tm,
    float* __restrict__ Mp)
{
    __shared__ unsigned sBu[2*8320];   // 65 KB
    const int tid  = threadIdx.x;
    const int lane = tid & 63;
    const int wid  = __builtin_amdgcn_readfirstlane(tid >> 6);
    const int bt   = wid & 1;
    const int q4   = (wid >> 1) * 4;
    const int colbase = blockIdx.x * 256;
    const int cgrp = tid & 31;
    const int kk2  = (tid >> 5) * 2;
    const int jp   = (kk2 & 7) >> 1;

#define TLOAD(TT, G0,G1,G2,G3) { \
    const float* r0_ = Tm + (size_t)((TT)*32 + kk2)*NCOL + colbase + cgrp*8; \
    G0 = *(const float4*)(r0_); \
    G1 = *(const float4*)(r0_ + 4); \
    G2 = *(const float4*)(r0_ + NCOL); \
    G3 = *(const float4*)(r0_ + NCOL + 4); }
#define ALOAD(TT, H, L_) { \
    H  = *(const short8v*)(Af + (TT)*1024 + bt*512 + lane*8); \
    L_ = *(const short8v*)(Af + ALO + (TT)*1024 + bt*512 + lane*8); }
#define CVT_WRITE(NB_, G0,G1,G2,G3) { \
    unsigned* dH = sBu + (NB_)*8320; \
    unsigned* dL = dH + 4160; \
    const float e0[8] = {G0.x,G0.y,G0.z,G0.w,G1.x,G1.y,G1.z,G1.w}; \
    const float e1[8] = {G2.x,G2.y,G2.z,G2.w,G3.x,G3.y,G3.z,G3.w}; \
    _Pragma("unroll") \
    for (int c = 0; c < 8; ++c) { \
        const int C  = cgrp*8 + c; \
        const int o  = (C>>4)*260 + ((((kk2>>3)&3)<<4) + (C&15))*4 + jp; \
        const ushort h0 = f2bf_hw(e0[c]), h1 = f2bf_hw(e1[c]); \
        dH[o] = (unsigned)h0 | ((unsigned)h1 << 16); \
        union { float f; unsigned u; } s0, s1; \
        s0.f = e0[c] - bf2f(h0); s1.f = e1[c] - bf2f(h1); \
        dL[o] = (s0.u >> 16) | (s1.u & 0xFFFF0000u);   /* trunc lo */ \
    } }
#define CONSUME(CUR) { \
    const ushort* bbase = (const ushort*)sBu + (CUR)*16640 + lane*8; \
    const short8v bHi0 = *(const short8v*)(bbase + (q4+0)*520); \
    const short8v bLo0 = *(const short8v*)(bbase + (q4+0)*520 + 8320); \
    acc0 = __builtin_amdgcn_mfma_f32_16x16x32_bf16(aHi, bHi0, acc0, 0,0,0); \
    acc0 = __builtin_amdgcn_mfma_f32_16x16x32_bf16(aHi, bLo0, acc0, 0,0,0); \
    acc0 = __builtin_amdgcn_mfma_f32_16x16x32_bf16(aLo, bHi0, acc0, 0,0,0); \
    const short8v bHi1 = *(const short8v*)(bbase + (q4+1)*520); \
    const short8v bLo1 = *(const short8v*)(bbase + (q4+1)*520 + 8320); \
    acc1 = __builtin_amdgcn_mfma_f32_16x16x32_bf16(aHi, bHi1, acc1, 0,0,0); \
    acc1 = __builtin_amdgcn_mfma_f32_16x16x32_bf16(aHi, bLo1, acc1, 0,0,0); \
    acc1 = __builtin_amdgcn_mfma_f32_16x16x32_bf16(aLo, bHi1, acc1, 0,0,0); \
    const short8v bHi2 = *(const short8v*)(bbase + (q4+2)*520); \
    const short8v bLo2 = *(const short8v*)(bbase + (q4+2)*520 + 8320); \
    acc2 = __builtin_amdgcn_mfma_f32_16x16x32_bf16(aHi, bHi2, acc2, 0,0,0); \
    acc2 = __builtin_amdgcn_mfma_f32_16x16x32_bf16(aHi, bLo2, acc2, 0,0,0); \
    acc2 = __builtin_amdgcn_mfma_f32_16x16x32_bf16(aLo, bHi2, acc2, 0,0,0); \
    const short8v bHi3 = *(const short8v*)(bbase + (q4+3)*520); \
    const short8v bLo3 = *(const short8v*)(bbase + (q4+3)*520 + 8320); \
    acc3 = __builtin_amdgcn_mfma_f32_16x16x32_bf16(aHi, bHi3, acc3, 0,0,0); \
    acc3 = __builtin_amdgcn_mfma_f32_16x16x32_bf16(aHi, bLo3, acc3, 0,0,0); \
    acc3 = __builtin_amdgcn_mfma_f32_16x16x32_bf16(aLo, bHi3, acc3, 0,0,0); }

    f32x4 acc0 = {0,0,0,0}, acc1 = {0,0,0,0}, acc2 = {0,0,0,0}, acc3 = {0,0,0,0};
    float4 gA0,gA1,gA2,gA3, gB0,gB1,gB2,gB3;
    short8v aHi, aLo, anHi, anLo;

    // prologue: L(0)->RA, L(1)->RB, A(0); stage tile 0; L(2)->RA
    TLOAD(0, gA0,gA1,gA2,gA3)
    TLOAD(1, gB0,gB1,gB2,gB3)
    ALOAD(0, aHi, aLo)
    CVT_WRITE(0, gA0,gA1,gA2,gA3)      // waits L(0) only (vmcnt counted)
    TLOAD(2, gA0,gA1,gA2,gA3)
    __syncthreads();

    for (int t = 0; t < NKS; t += 2) {
        // even phase: tile t from buf0
        if (t+1 < NKS) ALOAD(t+1, anHi, anLo)   // A before any new T loads
        CONSUME(0)
        __syncthreads();
        if (t+1 < NKS) {
            CVT_WRITE(1, gB0,gB1,gB2,gB3)       // L(t+1), landed
            if (t+3 < NKS) TLOAD(t+3, gB0,gB1,gB2,gB3)
            __syncthreads();
            aHi = anHi; aLo = anLo;
            // odd phase: tile t+1 from buf1
            if (t+2 < NKS) ALOAD(t+2, anHi, anLo)
            CONSUME(1)
            __syncthreads();
            if (t+2 < NKS) {
                CVT_WRITE(0, gA0,gA1,gA2,gA3)   // L(t+2)
                if (t+4 < NKS) TLOAD(t+4, gA0,gA1,gA2,gA3)
                __syncthreads();
                aHi = anHi; aLo = anLo;
            }
        }
    }

    const int colq = colbase + q4*16 + (lane & 15);
    const int brow = bt*16 + (lane >> 4)*4;
#define WB(ACC, I) { \
    _Pragma("unroll") \
    for (int r = 0; r < 4; ++r) \
        Mp[(size_t)(brow + r)*NCOL + colq + (I)*16] = ACC[r]; }
    WB(acc0, 0) WB(acc1, 1) WB(acc2, 2) WB(acc3, 3)
#undef WB
#undef CONSUME
#undef CVT_WRITE
#undef ALOAD
#undef TLOAD
}

// K3 v2: 16 d's/block x 512 blocks, rows padded to 20 floats ->
// conflict-free ds_read_b128; bit-identical f-order. (143.7 champion part)
__global__ __launch_bounds__(256) void k3_pairs(
    const float* __restrict__ Mp, float* __restrict__ outS)
{
    __shared__ float sM[32*16*20];     // 40960 B
    const int tid = threadIdx.x;
    const int dd0 = blockIdx.x * 16;
    for (int idx = tid; idx < 32*16*16; idx += 256) {
        const int i = idx >> 8, rem = idx & 255, d = rem >> 4, f = rem & 15;
        sM[(i*16 + d)*20 + f] = Mp[(size_t)i*NCOL + (size_t)dd0*16 + rem];
    }
    __syncthreads();
    const int j = tid >> 3;
    for (int q = 0; q < 2; ++q) {
        const int d = (tid & 7) + q*8;
        const float* pj = sM + (j*16 + d)*20;
        const float4 m0 = *(const float4*)(pj);
        const float4 m1 = *(const float4*)(pj + 4);
        const float4 m2 = *(const float4*)(pj + 8);
        const float4 m3 = *(const float4*)(pj + 12);
        float acc = 0.f;
        for (int i = 0; i < 32; ++i) {
            const float* pi = sM + (i*16 + d)*20;
            const float4 p0 = *(const float4*)(pi);
            const float4 p1 = *(const float4*)(pi + 4);
            const float4 p2 = *(const float4*)(pi + 8);
            const float4 p3 = *(const float4*)(pi + 12);
            float dist = fabsf(p0.x - m0.x);
            dist += fabsf(p0.y - m0.y); dist += fabsf(p0.z - m0.z); dist += fabsf(p0.w - m0.w);
            dist += fabsf(p1.x - m1.x); dist += fabsf(p1.y - m1.y);
            dist += fabsf(p1.z - m1.z); dist += fabsf(p1.w - m1.w);
            dist += fabsf(p2.x - m2.x); dist += fabsf(p2.y - m2.y);
            dist += fabsf(p2.z - m2.z); dist += fabsf(p2.w - m2.w);
            dist += fabsf(p3.x - m3.x); dist += fabsf(p3.y - m3.y);
            dist += fabsf(p3.z - m3.z); dist += fabsf(p3.w - m3.w);
            acc += __expf(-dist);
        }
        outS[(size_t)j*D_OUT + dd0 + d] = acc - 1.0f;
    }
}

// K4: ConvTranspose2d, stride==kernel -> no overlap. Unchanged.
__global__ __launch_bounds__(256) void k4_deconv(
    const float* __restrict__ outS, const float* __restrict__ wd,
    float* __restrict__ out)
{
    __shared__ float sO[32*256];
    __shared__ float sWd[32*16];
    const int b   = blockIdx.x >> 5;
    const int oc  = blockIdx.x & 31;
    const int tid = threadIdx.x;
    for (int idx = tid; idx < 8192; idx += 256) sO[idx] = outS[(size_t)b*D_OUT + idx];
    for (int idx = tid; idx < 512; idx += 256) {
        const int ic = idx >> 4, r = idx & 15;
        sWd[idx] = wd[((ic*32 + oc) << 4) + r];
    }
    __syncthreads();
    float* ob = out + (size_t)b*BSTRIDE + (size_t)(128 + oc)*4096;
    for (int s = 0; s < 16; ++s) {
        const int p  = tid + (s << 8);
        const int i  = p >> 6, jc = p & 63;
        const int si = i >> 2, ki = i & 3, sj = jc >> 2, kj = jc & 3;
        float acc = 0.f;
        #pragma unroll
        for (int ic = 0; ic < 32; ++ic)
            acc += sO[ic*256 + si*16 + sj] * sWd[ic*16 + ki*4 + kj];
        ob[p] = acc;
    }
}

extern "C" void kernel_launch(void* const* d_in, const int* in_sizes, int n_in,
                              void* d_out, int out_size, void* d_ws, size_t ws_size,
                              hipStream_t stream) {
    const float* x  = (const float*)d_in[0];
    const float* wc = (const float*)d_in[1];
    const float* Tm = (const float*)d_in[2];
    const float* wd = (const float*)d_in[3];
    float* out  = (float*)d_out;
    ushort* Af  = (ushort*)d_ws;                       // 96 KB @ 0
    float* Mp   = (float*)((char*)d_ws + (1 << 20));   // 16.8 MB @ 1 MB
    float* outS = (float*)((char*)d_ws + (72 << 20));  // 1 MB @ 72 MB

    k1_conv_copy<<<NB*TSP, 256, 0, stream>>>(x, wc, out, Af);                   // 512 blocks
    k2_gemm    <<<NCOL/256, 512, 0, stream>>>(Af, Tm, Mp);                      // 512 blocks
    k3_pairs   <<<D_OUT/16, 256, 0, stream>>>(Mp, outS);                        // 512 blocks
    k4_deconv  <<<NB*OUTF, 256, 0, stream>>>(outS, wd, out);                    // 1024 blocks
}

// Round 30
// 142.890 us; speedup vs baseline: 1.0634x; 1.0634x over previous
//
#include <hip/hip_runtime.h>

// ============================================================================
// FINAL CHAMPION (R27-submitted, measured 143.7 us in R28; restored after
// v22-single-shot regressed to 151.9 in R29).
// Session: 237.6 -> 143.7 (-40%). Wins: R13 spill fix, v21 split-bf16 MFMA
// (M ~= Ahi*Bhi+Ahi*Blo+Alo*Bhi, fp32 accum, absmax bit-identical 0.04211426),
// R27 k3 vectorization (20-float pad -> conflict-free ds_read_b128).
// ============================================================================

// Problem constants
#define NB      32
#define INF     128
#define NPIX    64
#define TSP     16
#define OUTF    32
#define FF      16
#define D_IN    768
#define D_OUT   8192
#define NCOL    (D_OUT*FF)   // 131072
#define OUTCH   160
#define BSTRIDE 655360
#define NKS     24           // K-steps of 32 (768/32)
#define ALO     24576        // Af lo-part offset (ushorts)

typedef __attribute__((ext_vector_type(8))) short short8v;  // 8 bf16
typedef __attribute__((ext_vector_type(4))) float f32x4;

static __device__ __forceinline__ ushort f2bf(float f) {
    union { float f; unsigned u; } v; v.f = f;
    return (ushort)((v.u + 0x7FFF + ((v.u >> 16) & 1)) >> 16);   // RNE
}
static __device__ __forceinline__ float bf2f(ushort h) {
    union { unsigned u; float f; } v; v.u = ((unsigned)h) << 16; return v.f;
}

// K1: fused strided conv + x->out copy. Emits A as SPLIT-bf16 MFMA
// A-fragments (layout: lane = ((k&31)>>3)*16 + (b&15), j = k&7).
__global__ __launch_bounds__(256) void k1_conv_copy(
    const float* __restrict__ x, const float* __restrict__ wc,
    float* __restrict__ out, ushort* __restrict__ Af)
{
    __shared__ float sW[3*128*16];
    __shared__ float sP[16][16][3];
    const int b   = blockIdx.x >> 4;
    const int oi  = blockIdx.x & 15;
    const int tid = threadIdx.x;
    for (int idx = tid; idx < 6144; idx += 256) sW[idx] = wc[idx];
    __syncthreads();
    const int icg = tid >> 4;
    const int j   = tid & 15;
    float a0 = 0.f, a1 = 0.f, a2 = 0.f;
    for (int ic8 = 0; ic8 < 8; ++ic8) {
        const int ic = icg*8 + ic8;
        #pragma unroll
        for (int ki = 0; ki < 4; ++ki) {
            const int row = 4*oi + ki;
            const float4 xv = *(const float4*)(x + ((size_t)(b*INF+ic)*NPIX + row)*NPIX + 4*j);
            *(float4*)(out + ((size_t)(b*OUTCH+ic)*NPIX + row)*NPIX + 4*j) = xv;
            const float* w0 = sW + ((0*INF+ic)*4 + ki)*4;
            const float* w1 = sW + ((1*INF+ic)*4 + ki)*4;
            const float* w2 = sW + ((2*INF+ic)*4 + ki)*4;
            a0 += xv.x*w0[0] + xv.y*w0[1] + xv.z*w0[2] + xv.w*w0[3];
            a1 += xv.x*w1[0] + xv.y*w1[1] + xv.z*w1[2] + xv.w*w1[3];
            a2 += xv.x*w2[0] + xv.y*w2[1] + xv.z*w2[2] + xv.w*w2[3];
        }
    }
    sP[icg][j][0] = a0; sP[icg][j][1] = a1; sP[icg][j][2] = a2;
    __syncthreads();
    if (tid < 48) {
        const int c3 = tid >> 4, jj = tid & 15;
        float s = 0.f;
        #pragma unroll
        for (int g = 0; g < 16; ++g) s += sP[g][jj][c3];
        const int k  = c3*256 + oi*16 + jj;
        const ushort hi = f2bf(s);
        const ushort lo = f2bf(s - bf2f(hi));
        const int fa = (k>>5)*1024 + (b>>4)*512 + ((((k>>3)&3)<<4) + (b&15))*8 + (k&7);
        Af[fa] = hi; Af[ALO + fa] = lo;
    }
}

// K2 v21 (champion): split-bf16 MFMA. Block 256 cols x 32 b, full K in
// acc (4 x f32x4); staging: fp32 global -> split cvt -> ds_write b32
// pairs in B-frag layout (pad 520 ushorts/ct); consume = ds_read_b128 +
// 12 MFMA/step. A-loads issued BEFORE T-loads (in-order vmcnt retire).
__global__ __launch_bounds__(512, 4) void k2_gemm(
    const ushort* __restrict__ Af, const float* __restrict__ Tm,
    float* __restrict__ Mp)
{
    __shared__ unsigned sBu[2*8320];
    const int tid  = threadIdx.x;
    const int lane = tid & 63;
    const int wid  = __builtin_amdgcn_readfirstlane(tid >> 6);
    const int bt   = wid & 1;
    const int q4   = (wid >> 1) * 4;
    const int colbase = blockIdx.x * 256;
    const int cgrp = tid & 31;
    const int kk2  = (tid >> 5) * 2;

    f32x4 acc0 = {0,0,0,0}, acc1 = {0,0,0,0}, acc2 = {0,0,0,0}, acc3 = {0,0,0,0};

    const int jp = (kk2 & 7) >> 1;
#define CVT_WRITE(NB_, G0,G1,G2,G3) { \
    unsigned* dH = sBu + (NB_)*8320; \
    unsigned* dL = dH + 4160; \
    const float e0[8] = {G0.x,G0.y,G0.z,G0.w,G1.x,G1.y,G1.z,G1.w}; \
    const float e1[8] = {G2.x,G2.y,G2.z,G2.w,G3.x,G3.y,G3.z,G3.w}; \
    _Pragma("unroll") \
    for (int c = 0; c < 8; ++c) { \
        const int C  = cgrp*8 + c; \
        const int o  = (C>>4)*260 + ((((kk2>>3)&3)<<4) + (C&15))*4 + jp; \
        const ushort h0 = f2bf(e0[c]), h1 = f2bf(e1[c]); \
        dH[o] = (unsigned)h0 | ((unsigned)h1 << 16); \
        const ushort l0 = f2bf(e0[c] - bf2f(h0)), l1 = f2bf(e1[c] - bf2f(h1)); \
        dL[o] = (unsigned)l0 | ((unsigned)l1 << 16); \
    } }

    {
        const float* r0 = Tm + (size_t)kk2*NCOL + colbase + cgrp*8;
        const float4 g0 = *(const float4*)(r0);
        const float4 g1 = *(const float4*)(r0 + 4);
        const float4 g2 = *(const float4*)(r0 + NCOL);
        const float4 g3 = *(const float4*)(r0 + NCOL + 4);
        CVT_WRITE(0, g0, g1, g2, g3)
    }
    __syncthreads();

    for (int t = 0; t < NKS; ++t) {
        const int cur = t & 1;
        const short8v aHi = *(const short8v*)(Af + t*1024 + bt*512 + lane*8);
        const short8v aLo = *(const short8v*)(Af + ALO + t*1024 + bt*512 + lane*8);
        float4 g0, g1, g2, g3;
        const bool more = (t + 1 < NKS);
        if (more) {
            const float* r0 = Tm + (size_t)((t+1)*32 + kk2)*NCOL + colbase + cgrp*8;
            g0 = *(const float4*)(r0);
            g1 = *(const float4*)(r0 + 4);
            g2 = *(const float4*)(r0 + NCOL);
            g3 = *(const float4*)(r0 + NCOL + 4);
        }
        const ushort* bbase = (const ushort*)sBu + cur*16640 + lane*8;
        {
            const short8v bHi0 = *(const short8v*)(bbase + (q4+0)*520);
            const short8v bLo0 = *(const short8v*)(bbase + (q4+0)*520 + 8320);
            acc0 = __builtin_amdgcn_mfma_f32_16x16x32_bf16(aHi, bHi0, acc0, 0,0,0);
            acc0 = __builtin_amdgcn_mfma_f32_16x16x32_bf16(aHi, bLo0, acc0, 0,0,0);
            acc0 = __builtin_amdgcn_mfma_f32_16x16x32_bf16(aLo, bHi0, acc0, 0,0,0);
            const short8v bHi1 = *(const short8v*)(bbase + (q4+1)*520);
            const short8v bLo1 = *(const short8v*)(bbase + (q4+1)*520 + 8320);
            acc1 = __builtin_amdgcn_mfma_f32_16x16x32_bf16(aHi, bHi1, acc1, 0,0,0);
            acc1 = __builtin_amdgcn_mfma_f32_16x16x32_bf16(aHi, bLo1, acc1, 0,0,0);
            acc1 = __builtin_amdgcn_mfma_f32_16x16x32_bf16(aLo, bHi1, acc1, 0,0,0);
            const short8v bHi2 = *(const short8v*)(bbase + (q4+2)*520);
            const short8v bLo2 = *(const short8v*)(bbase + (q4+2)*520 + 8320);
            acc2 = __builtin_amdgcn_mfma_f32_16x16x32_bf16(aHi, bHi2, acc2, 0,0,0);
            acc2 = __builtin_amdgcn_mfma_f32_16x16x32_bf16(aHi, bLo2, acc2, 0,0,0);
            acc2 = __builtin_amdgcn_mfma_f32_16x16x32_bf16(aLo, bHi2, acc2, 0,0,0);
            const short8v bHi3 = *(const short8v*)(bbase + (q4+3)*520);
            const short8v bLo3 = *(const short8v*)(bbase + (q4+3)*520 + 8320);
            acc3 = __builtin_amdgcn_mfma_f32_16x16x32_bf16(aHi, bHi3, acc3, 0,0,0);
            acc3 = __builtin_amdgcn_mfma_f32_16x16x32_bf16(aHi, bLo3, acc3, 0,0,0);
            acc3 = __builtin_amdgcn_mfma_f32_16x16x32_bf16(aLo, bHi3, acc3, 0,0,0);
        }
        __syncthreads();
        if (more) {
            CVT_WRITE(cur ^ 1, g0, g1, g2, g3)
            __syncthreads();
        }
    }
#undef CVT_WRITE

    const int colq = colbase + q4*16 + (lane & 15);
    const int brow = bt*16 + (lane >> 4)*4;
#define WB(ACC, I) { \
    _Pragma("unroll") \
    for (int r = 0; r < 4; ++r) \
        Mp[(size_t)(brow + r)*NCOL + colq + (I)*16] = ACC[r]; }
    WB(acc0, 0) WB(acc1, 1) WB(acc2, 2) WB(acc3, 3)
#undef WB
}

// K3 v2: 16 d's/block x 512 blocks (40KB LDS -> 2 blocks/CU); rows padded
// to 20 floats (16B-aligned) -> conflict-free ds_read_b128; scalar f-order
// -> bit-identical output.
__global__ __launch_bounds__(256) void k3_pairs(
    const float* __restrict__ Mp, float* __restrict__ outS)
{
    __shared__ float sM[32*16*20];     // 40960 B
    const int tid = threadIdx.x;
    const int dd0 = blockIdx.x * 16;
    for (int idx = tid; idx < 32*16*16; idx += 256) {
        const int i = idx >> 8, rem = idx & 255, d = rem >> 4, f = rem & 15;
        sM[(i*16 + d)*20 + f] = Mp[(size_t)i*NCOL + (size_t)dd0*16 + rem];
    }
    __syncthreads();
    const int j = tid >> 3;
    for (int q = 0; q < 2; ++q) {
        const int d = (tid & 7) + q*8;
        const float* pj = sM + (j*16 + d)*20;
        const float4 m0 = *(const float4*)(pj);
        const float4 m1 = *(const float4*)(pj + 4);
        const float4 m2 = *(const float4*)(pj + 8);
        const float4 m3 = *(const float4*)(pj + 12);
        float acc = 0.f;
        for (int i = 0; i < 32; ++i) {
            const float* pi = sM + (i*16 + d)*20;
            const float4 p0 = *(const float4*)(pi);
            const float4 p1 = *(const float4*)(pi + 4);
            const float4 p2 = *(const float4*)(pi + 8);
            const float4 p3 = *(const float4*)(pi + 12);
            float dist = fabsf(p0.x - m0.x);
            dist += fabsf(p0.y - m0.y); dist += fabsf(p0.z - m0.z); dist += fabsf(p0.w - m0.w);
            dist += fabsf(p1.x - m1.x); dist += fabsf(p1.y - m1.y);
            dist += fabsf(p1.z - m1.z); dist += fabsf(p1.w - m1.w);
            dist += fabsf(p2.x - m2.x); dist += fabsf(p2.y - m2.y);
            dist += fabsf(p2.z - m2.z); dist += fabsf(p2.w - m2.w);
            dist += fabsf(p3.x - m3.x); dist += fabsf(p3.y - m3.y);
            dist += fabsf(p3.z - m3.z); dist += fabsf(p3.w - m3.w);
            acc += __expf(-dist);
        }
        outS[(size_t)j*D_OUT + dd0 + d] = acc - 1.0f;
    }
}

// K4: ConvTranspose2d, stride==kernel -> no overlap. Unchanged.
__global__ __launch_bounds__(256) void k4_deconv(
    const float* __restrict__ outS, const float* __restrict__ wd,
    float* __restrict__ out)
{
    __shared__ float sO[32*256];
    __shared__ float sWd[32*16];
    const int b   = blockIdx.x >> 5;
    const int oc  = blockIdx.x & 31;
    const int tid = threadIdx.x;
    for (int idx = tid; idx < 8192; idx += 256) sO[idx] = outS[(size_t)b*D_OUT + idx];
    for (int idx = tid; idx < 512; idx += 256) {
        const int ic = idx >> 4, r = idx & 15;
        sWd[idx] = wd[((ic*32 + oc) << 4) + r];
    }
    __syncthreads();
    float* ob = out + (size_t)b*BSTRIDE + (size_t)(128 + oc)*4096;
    for (int s = 0; s < 16; ++s) {
        const int p  = tid + (s << 8);
        const int i  = p >> 6, jc = p & 63;
        const int si = i >> 2, ki = i & 3, sj = jc >> 2, kj = jc & 3;
        float acc = 0.f;
        #pragma unroll
        for (int ic = 0; ic < 32; ++ic)
            acc += sO[ic*256 + si*16 + sj] * sWd[ic*16 + ki*4 + kj];
        ob[p] = acc;
    }
}

extern "C" void kernel_launch(void* const* d_in, const int* in_sizes, int n_in,
                              void* d_out, int out_size, void* d_ws, size_t ws_size,
                              hipStream_t stream) {
    const float* x  = (const float*)d_in[0];
    const float* wc = (const float*)d_in[1];
    const float* Tm = (const float*)d_in[2];
    const float* wd = (const float*)d_in[3];
    float* out  = (float*)d_out;
    ushort* Af  = (ushort*)d_ws;                       // 96 KB @ 0
    float* Mp   = (float*)((char*)d_ws + (1 << 20));   // 16.8 MB @ 1 MB
    float* outS = (float*)((char*)d_ws + (72 << 20));  // 1 MB @ 72 MB

    k1_conv_copy<<<NB*TSP, 256, 0, stream>>>(x, wc, out, Af);                   // 512 blocks
    k2_gemm    <<<NCOL/256, 512, 0, stream>>>(Af, Tm, Mp);                      // 512 blocks
    k3_pairs   <<<D_OUT/16, 256, 0, stream>>>(Mp, outS);                        // 512 blocks
    k4_deconv  <<<NB*OUTF, 256, 0, stream>>>(outS, wd, out);                    // 1024 blocks
}